// Round 1
// baseline (839.274 us; speedup 1.0000x reference)
//
#include <hip/hip_runtime.h>
#include <math.h>

// HyenaFilter: y = irfft(rfft(x,2L) * rfft(k,2L))[..., :L] + x*bias
// Register-blocked mixed-radix [16,16,16,2] FFT. This revision:
//  - hand-folded XOR-swizzle addressing (1 XOR/access, ds-offset-foldable)
//  - table twiddles (TL*TH factorization for pass A) replacing 14-deep cmul chains
//  - radix-2 passes fused into the spectral multiply (quad {k,4096-k,4096+k,8192-k})
//  - pruned first forward pass (upper half of input is zero)
//  - H in row-major [8192][16]; k_init+k_mlp merged into k_pre

#define LSEQ 8192
#define NCH 768
#define NBATCH 8
#define NT 512

// ws layout (float offsets) — all tables fit in the pre-H region (no growth vs prev)
#define OFF_TWB  0        // 32 rows x 16 float2 : W16384^{32*q*m}   (pass B)
#define OFF_TW16 1024     // 2049 float2         : W16384^k, k<=2048
#define OFF_TL   5124     // 32 rows x 16 float2 : W16384^{2*a*m}    (pass A low)
#define OFF_TH   6148     // 16 rows x 16 float2 : W16384^{64*b*m}   (pass A high)
#define OFF_TWC  6660     // 2 rows x 16 float2  : W16384^{512*p*m}  (pass C)
#define OFF_H    10240    // 8192 x 16 floats (MLP features, row-major)
#define OFF_KF   141312   // 768 x 4096 float4 (S~, D~ per bin pair)

__device__ __forceinline__ float2 cadd(float2 a, float2 b){ return make_float2(a.x+b.x, a.y+b.y); }
__device__ __forceinline__ float2 csub(float2 a, float2 b){ return make_float2(a.x-b.x, a.y-b.y); }
__device__ __forceinline__ float2 cmul(float2 a, float2 b){ return make_float2(a.x*b.x - a.y*b.y, a.x*b.y + a.y*b.x); }
__device__ __forceinline__ float2 mni(float2 a){ return make_float2(a.y, -a.x); }  // * -i

// generic swizzle (used only in the 4-iteration spectral stage)
__device__ __forceinline__ int IDX(int i){ return i ^ (((i>>4) ^ (i>>8)) & 15); }
// digit-reversal: bin k -> slot after DIF passes [16(512),16(32),16(2)] (pre-r2, slot even)
__device__ __forceinline__ int drev(int k){
    return ((k & 15) << 9) | (((k >> 4) & 15) << 5) | (((k >> 8) & 15) << 1) | (k >> 12);
}

#define C1 0.923879532511286756f
#define S1 0.382683432365089772f
#define R2 0.707106781186547524f

// natural-in DFT-16; output bin m in q[rv[m]]. FULL=false: inputs 8..15 are
// pre-duplicated copies of 0..7 (zero upper half), stage-1 add/sub skipped.
template<bool FULL>
__device__ __forceinline__ void dft16(float2 q[16]) {
    if constexpr (FULL) {
#pragma unroll
        for (int j = 0; j < 8; ++j) { float2 u=q[j], v=q[j+8]; q[j]=cadd(u,v); q[j+8]=csub(u,v); }
    }
    q[9]  = cmul(q[9],  make_float2( C1,-S1));
    q[10] = cmul(q[10], make_float2( R2,-R2));
    q[11] = cmul(q[11], make_float2( S1,-C1));
    q[12] = mni(q[12]);
    q[13] = cmul(q[13], make_float2(-S1,-C1));
    q[14] = cmul(q[14], make_float2(-R2,-R2));
    q[15] = cmul(q[15], make_float2(-C1,-S1));
#pragma unroll
    for (int b = 0; b < 16; b += 8) {
#pragma unroll
        for (int j = 0; j < 4; ++j) { float2 u=q[b+j], v=q[b+j+4]; q[b+j]=cadd(u,v); q[b+j+4]=csub(u,v); }
        q[b+5] = cmul(q[b+5], make_float2( R2,-R2));
        q[b+6] = mni(q[b+6]);
        q[b+7] = cmul(q[b+7], make_float2(-R2,-R2));
    }
#pragma unroll
    for (int b = 0; b < 16; b += 4) {
        float2 u0=q[b], v0=q[b+2], u1=q[b+1], v1=q[b+3];
        q[b]=cadd(u0,v0); q[b+2]=csub(u0,v0);
        q[b+1]=cadd(u1,v1); q[b+3]=mni(csub(u1,v1));
    }
#pragma unroll
    for (int b = 0; b < 16; b += 2) { float2 u=q[b], v=q[b+1]; q[b]=cadd(u,v); q[b+1]=csub(u,v); }
}

// Hand-folded swizzled addressing. For tid<512 the pass strides are bit-disjoint,
// so IDX(base+p+r*L) == (sb ^ C_r) + (r*L) with per-thread sb and constant C_r.
// (Verified numerically against IDX() for multiple (tid,r) samples per pass.)
template<int PASS>
__device__ __forceinline__ int psb(int tid) {
    if constexpr (PASS == 0) {               // L=512, p=tid
        return tid ^ (((tid>>4) ^ (tid>>8)) & 15);
    } else if constexpr (PASS == 1) {        // L=32, base=(tid>>5)<<9, p=tid&31
        int p = tid & 31, hb = tid >> 5;
        return ((hb<<9) | p) ^ (((p>>4) ^ (hb<<1)) & 15);
    } else {                                 // L=2, base=(tid>>1)<<5, p=tid&1
        int h = tid >> 1;
        return ((h<<5) | (tid&1)) ^ (((h<<1) ^ (h>>3)) & 15);
    }
}
template<int PASS>
__device__ __forceinline__ int paddr(int sb, int r) {
    if constexpr (PASS == 0)      return (sb ^ (2*(r&7))) + (r<<9);
    else if constexpr (PASS == 1) return (sb ^ ((2*(r&7)) ^ (r>>3))) + (r<<5);
    else                          return sb ^ ((r<<1) ^ (r>>3));
}

// twiddle row pointers (rows of 16 float2 = 8 float4, 128B aligned)
template<int PASS>
__device__ __forceinline__ void twrows(const float* ws, int tid, const float4*& rA, const float4*& rB) {
    if constexpr (PASS == 0) {
        rA = (const float4*)(ws + OFF_TL) + ((tid & 31) << 3);
        rB = (const float4*)(ws + OFF_TH) + ((tid >> 5) << 3);
    } else if constexpr (PASS == 1) {
        rA = (const float4*)(ws + OFF_TWB) + ((tid & 31) << 3); rB = rA;
    } else {
        rA = (const float4*)(ws + OFF_TWC) + ((tid & 1) << 3); rB = rA;
    }
}
template<int PASS>
__device__ __forceinline__ void twget(const float4* rA, const float4* rB, int j, float2& w0, float2& w1) {
    float4 a = rA[j];
    if constexpr (PASS == 0) {   // W^{p*m} = TL[p&31][m] * TH[p>>5][m]
        float4 b = rB[j];
        w0 = cmul(make_float2(a.x,a.y), make_float2(b.x,b.y));
        w1 = cmul(make_float2(a.z,a.w), make_float2(b.z,b.w));
    } else {
        w0 = make_float2(a.x, a.y);
        w1 = make_float2(a.z, a.w);
    }
}

// One radix-16 pass. DIT=false: dft16 then q[rv[m]] *= W^{pm} (DIF fwd).
// DIT=true: q[r] *= W^{pr} then dft16. PRUNED (fwd pass A only): upper 8 inputs zero.
template<int PASS, bool DIT, bool PRUNED>
__device__ __forceinline__ void r16p(float2* lds, int tid, const float* __restrict__ ws) {
    static constexpr int RV[16] = {0,8,4,12,2,10,6,14,1,9,5,13,3,11,7,15};
    const int sb = psb<PASS>(tid);
    const float4 *rA, *rB;
    twrows<PASS>(ws, tid, rA, rB);
    float2 q[16];
    if constexpr (PRUNED) {
#pragma unroll
        for (int r = 0; r < 8; ++r) { q[r] = lds[paddr<PASS>(sb, r)]; q[r+8] = q[r]; }
    } else {
#pragma unroll
        for (int r = 0; r < 16; ++r) q[r] = lds[paddr<PASS>(sb, r)];
    }
    if constexpr (DIT) {
#pragma unroll
        for (int j = 0; j < 8; ++j) {
            float2 w0, w1; twget<PASS>(rA, rB, j, w0, w1);
            if (j) q[2*j] = cmul(q[2*j], w0);
            q[2*j+1] = cmul(q[2*j+1], w1);
        }
        dft16<true>(q);
    } else {
        dft16<!PRUNED>(q);
#pragma unroll
        for (int j = 0; j < 8; ++j) {
            float2 w0, w1; twget<PASS>(rA, rB, j, w0, w1);
            if (j) q[RV[2*j]] = cmul(q[RV[2*j]], w0);
            q[RV[2*j+1]] = cmul(q[RV[2*j+1]], w1);
        }
    }
#pragma unroll
    for (int m = 0; m < 16; ++m) lds[paddr<PASS>(sb, m)] = q[RV[m]];
}

// spectral multiply for bin pair (k, 8192-k): o1/o2 are swapped v'[k], v'[8192-k]
__device__ __forceinline__ void specpair(float2 V1, float2 V2, float4 kv, float2 W,
                                         float2& o1, float2& o2) {
    float2 Eh = make_float2(V1.x + V2.x, V1.y - V2.y);
    float2 Oh = make_float2(V1.y + V2.y, V2.x - V1.x);
    float2 S = make_float2(kv.x, kv.y);
    float a = W.x*kv.z, b = W.y*kv.w, cc = W.x*kv.w, dd = W.y*kv.z;
    float2 T  = make_float2(a - b, cc + dd);
    float2 T2 = make_float2(a + b, cc - dd);
    float2 Ep = cadd(cmul(Eh, S), cmul(Oh, T));
    float2 Op = cadd(cmul(Eh, T2), cmul(Oh, S));
    o1 = make_float2(Ep.y + Op.x, Ep.x - Op.y);
    o2 = make_float2(Op.x - Ep.y, Ep.x + Op.y);
}

// merged init (block 0: twiddle tables via double-precision factor tables) + MLP (blocks 1..16)
__global__ __launch_bounds__(512) void k_pre(const float* __restrict__ z, const float* __restrict__ freq,
        const float* __restrict__ W0, const float* __restrict__ b0,
        const float* __restrict__ W1, const float* __restrict__ b1,
        const float* __restrict__ W2, const float* __restrict__ b2,
        float* __restrict__ ws, float* __restrict__ H) {
    __shared__ double2 lA[128], lB[128];
    const int t = threadIdx.x;
    if (blockIdx.x == 0) {
        const double K = -2.0 * 3.14159265358979323846 / 16384.0;
        if (t < 128)      { double a = K * (double)(t << 7); lA[t] = make_double2(cos(a), sin(a)); }
        else if (t < 256) { int b = t - 128; double a = K * (double)b; lB[b] = make_double2(cos(a), sin(a)); }
        __syncthreads();
        auto wf = [&](int e) -> float2 {
            e &= 16383;
            double2 A = lA[e >> 7], B = lB[e & 127];
            return make_float2((float)(A.x*B.x - A.y*B.y), (float)(A.x*B.y + A.y*B.x));
        };
        float2* tw16 = (float2*)(ws + OFF_TW16);
        for (int k = t; k <= 2048; k += 512) tw16[k] = wf(k);
        if (t < 32) {
            float2* rowL = (float2*)(ws + OFF_TL)  + (t << 4);
            float2* rowB = (float2*)(ws + OFF_TWB) + (t << 4);
#pragma unroll
            for (int m = 0; m < 16; ++m) { rowL[m] = wf(2*t*m); rowB[m] = wf(32*t*m); }
        } else if (t < 48) {
            int b = t - 32;
            float2* rowH = (float2*)(ws + OFF_TH) + (b << 4);
#pragma unroll
            for (int m = 0; m < 16; ++m) rowH[m] = wf(64*b*m);
        } else if (t < 50) {
            int c2 = t - 48;
            float2* rowC = (float2*)(ws + OFF_TWC) + (c2 << 4);
#pragma unroll
            for (int m = 0; m < 16; ++m) rowC[m] = wf(512*c2*m);
        }
    } else {
        const int j = ((blockIdx.x - 1) << 9) + t;
        const float z0 = z[j*3+0], z1 = z[j*3+1], z2 = z[j*3+2];
        float h[16], g[16];
#pragma unroll
        for (int m = 0; m < 16; ++m)
            h[m] = sinf(freq[m] * (z0*W0[m] + z1*W0[16+m] + z2*W0[32+m] + b0[m]));
#pragma unroll
        for (int m = 0; m < 16; ++m) {
            float a = b1[m];
#pragma unroll
            for (int p = 0; p < 16; ++p) a += h[p] * W1[p*16+m];
            g[m] = sinf(freq[m] * a);
        }
#pragma unroll
        for (int m = 0; m < 16; ++m) {
            float a = b2[m];
#pragma unroll
            for (int p = 0; p < 16; ++p) a += g[p] * W2[p*16+m];
            h[m] = sinf(freq[m] * a);
        }
        float4* hp = (float4*)(H + (j << 4));   // row-major [8192][16]
        hp[0] = make_float4(h[0],  h[1],  h[2],  h[3]);
        hp[1] = make_float4(h[4],  h[5],  h[6],  h[7]);
        hp[2] = make_float4(h[8],  h[9],  h[10], h[11]);
        hp[3] = make_float4(h[12], h[13], h[14], h[15]);
    }
}

// Per channel: filter -> pruned fwd FFT -> fused(r2+unpack) -> store (S~,D~)
__global__ __launch_bounds__(NT, 4) void k_filter(const float* __restrict__ H, const float* __restrict__ t,
        const float* __restrict__ deltas, const float* __restrict__ W3,
        const float* __restrict__ b3, const float* __restrict__ ws,
        float* __restrict__ KfF) {
    __shared__ float2 lds[LSEQ];
    const int c = blockIdx.x;
    const int tid = threadIdx.x;
    float4 w3a = make_float4(W3[0*NCH+c],  W3[1*NCH+c],  W3[2*NCH+c],  W3[3*NCH+c]);
    float4 w3b = make_float4(W3[4*NCH+c],  W3[5*NCH+c],  W3[6*NCH+c],  W3[7*NCH+c]);
    float4 w3c = make_float4(W3[8*NCH+c],  W3[9*NCH+c],  W3[10*NCH+c], W3[11*NCH+c]);
    float4 w3d = make_float4(W3[12*NCH+c], W3[13*NCH+c], W3[14*NCH+c], W3[15*NCH+c]);
    const float b3c = b3[c];
    const float ad = fabsf(deltas[c]);
    const int sbA = psb<0>(tid);
#pragma unroll 2
    for (int j = 0; j < 8; ++j) {
        int n = tid + (j << 9);
        const float4* hp = (const float4*)(H + (n << 5));
        float4 p0 = hp[0], p1 = hp[1], p2 = hp[2], p3 = hp[3];
        float4 q0 = hp[4], q1 = hp[5], q2 = hp[6], q3 = hp[7];
        float s0 = b3c + p0.x*w3a.x + p0.y*w3a.y + p0.z*w3a.z + p0.w*w3a.w
                       + p1.x*w3b.x + p1.y*w3b.y + p1.z*w3b.z + p1.w*w3b.w
                       + p2.x*w3c.x + p2.y*w3c.y + p2.z*w3c.z + p2.w*w3c.w
                       + p3.x*w3d.x + p3.y*w3d.y + p3.z*w3d.z + p3.w*w3d.w;
        float s1 = b3c + q0.x*w3a.x + q0.y*w3a.y + q0.z*w3a.z + q0.w*w3a.w
                       + q1.x*w3b.x + q1.y*w3b.y + q1.z*w3b.z + q1.w*w3b.w
                       + q2.x*w3c.x + q2.y*w3c.y + q2.z*w3c.z + q2.w*w3c.w
                       + q3.x*w3d.x + q3.y*w3d.y + q3.z*w3d.z + q3.w*w3d.w;
        float2 tv = ((const float2*)t)[n];
        lds[(sbA ^ (2*j)) + (j<<9)] = make_float2(s0 * expf(-tv.x*ad), s1 * expf(-tv.y*ad));
    }
    __syncthreads();
    r16p<0,false,true >(lds, tid, ws); __syncthreads();
    r16p<1,false,false>(lds, tid, ws); __syncthreads();
    r16p<2,false,false>(lds, tid, ws); __syncthreads();

    float4* kf4 = (float4*)KfF + (size_t)c * 4096;
    const float2* tw16 = (const float2*)(ws + OFF_TW16);
    const float sc = 1.0f / 32768.0f;
#pragma unroll 2
    for (int it = 0; it < 4; ++it) {
        int k  = tid + 1 + (it << 9);   // 1..2048
        int jj = 4096 - k;              // 2048..4095 (k=2048: idempotent dup)
        int pA = IDX(drev(k)), pB = IDX(drev(jj));
        float2 uA = lds[pA], vA = lds[pA^1];
        float2 uB = lds[pB], vB = lds[pB^1];
        float2 Vk = cadd(uA, vA), Vk4 = csub(uA, vA);   // bins k, k+4096
        float2 Vj = cadd(uB, vB), Vj4 = csub(uB, vB);   // bins jj, jj+4096 (=8192-k)
        float2 W  = tw16[k];
        float2 Wj = make_float2(-W.y, -W.x);            // tw16[4096-k]
        {
            float2 E = make_float2(Vk.x + Vj4.x, Vk.y - Vj4.y);
            float2 O = make_float2(Vk.y + Vj4.y, Vj4.x - Vk.x);
            float2 D = cmul(W, O);
            kf4[k] = make_float4(E.x*sc, E.y*sc, D.x*sc, D.y*sc);
        }
        {
            float2 E = make_float2(Vj.x + Vk4.x, Vj.y - Vk4.y);
            float2 O = make_float2(Vj.y + Vk4.y, Vk4.x - Vj.x);
            float2 D = cmul(Wj, O);
            kf4[jj] = make_float4(E.x*sc, E.y*sc, D.x*sc, D.y*sc);
        }
    }
    if (tid == 0) {
        float2 u = lds[0], v = lds[1];          // IDX(0)=0, IDX(1)=1
        float2 V0 = cadd(u, v), VN = csub(u, v);
        kf4[0] = make_float4((V0.x + V0.y)/16384.f, (V0.x - V0.y)/16384.f,
                             VN.x/8192.f, -VN.y/8192.f);
    }
}

// Per row: pack x -> pruned fwd FFT -> fused(r2 + spectral + inv-r2) -> DIT net -> out
__global__ __launch_bounds__(NT, 4) void k_main(const float* __restrict__ x, const float* __restrict__ ws,
        const float* __restrict__ KfF, const float* __restrict__ bias,
        float* __restrict__ out) {
    __shared__ float2 lds[LSEQ];
    const int bid = blockIdx.x;
    const int c = bid >> 3, bat = bid & 7;     // co-resident batches share Kf[c] in L2
    const int row = bat * NCH + c;
    const int tid = threadIdx.x;
    const float4* xrow4 = (const float4*)(x + (size_t)row * LSEQ);
    const float4* kf4 = (const float4*)KfF + (size_t)c * 4096;

    // staging addresses: IDX(2i) = (EB ^ (j<<2)) + (j<<10), IDX(2i+1) = that ^ 1
    const int EB = (tid << 1) ^ (((tid>>3) ^ (tid>>7)) & 15);
    float4 xs[4];
#pragma unroll
    for (int j = 0; j < 4; ++j) {
        float4 v = xrow4[tid + (j<<9)];
        xs[j] = v;
        int a0 = (EB ^ (j<<2)) + (j<<10);
        lds[a0]   = make_float2(v.x, v.y);
        lds[a0^1] = make_float2(v.z, v.w);
    }
    __syncthreads();
    r16p<0,false,true >(lds, tid, ws); __syncthreads();
    r16p<1,false,false>(lds, tid, ws); __syncthreads();
    r16p<2,false,false>(lds, tid, ws); __syncthreads();

    // fused fwd-r2 + spectral multiply + inverse-r2, per closed quad of bins
    {
        const float2* tw16 = (const float2*)(ws + OFF_TW16);
#pragma unroll 2
        for (int it = 0; it < 4; ++it) {
            int k  = tid + 1 + (it << 9);   // 1..2048
            int jj = 4096 - k;
            int pA = IDX(drev(k)), pB = IDX(drev(jj));
            float2 uA = lds[pA], vA = lds[pA^1];
            float2 uB = lds[pB], vB = lds[pB^1];
            float2 Vk = cadd(uA, vA), Vk4 = csub(uA, vA);   // bins k, k+4096
            float2 Vj = cadd(uB, vB), Vj4 = csub(uB, vB);   // bins jj, 8192-k
            float4 kvk = kf4[k], kvj = kf4[jj];
            float2 W  = tw16[k];
            float2 Wj = make_float2(-W.y, -W.x);
            float2 r1, r2, r1j, r2j;
            specpair(Vk, Vj4, kvk, W,  r1,  r2);   // v'[k],  v'[8192-k]
            specpair(Vj, Vk4, kvj, Wj, r1j, r2j);  // v'[jj], v'[4096+k]
            lds[pA]   = cadd(r1, r2j);  lds[pA^1] = csub(r1, r2j);
            lds[pB]   = cadd(r1j, r2);  lds[pB^1] = csub(r1j, r2);
        }
        if (tid == 0) {
            float2 u = lds[0], v = lds[1];
            float2 V0 = cadd(u, v), VN = csub(u, v);        // bins 0, 4096
            float4 kv = kf4[0];
            float U0 = V0.x + V0.y, UL = V0.x - V0.y;
            float re = U0*kv.x + UL*kv.y;
            float im = U0*kv.x - UL*kv.y;
            float2 s0 = make_float2(im, re);
            float2 P = make_float2(VN.x*kv.z + VN.y*kv.w, VN.x*kv.w - VN.y*kv.z);
            float2 s1 = make_float2(-P.y, P.x);
            lds[0] = cadd(s0, s1);
            lds[1] = csub(s0, s1);
        }
    }
    __syncthreads();

    r16p<2,true,false>(lds, tid, ws); __syncthreads();
    r16p<1,true,false>(lds, tid, ws); __syncthreads();
    r16p<0,true,false>(lds, tid, ws); __syncthreads();

    const float bc = bias[c];
    float4* orow4 = (float4*)(out + (size_t)row * LSEQ);
#pragma unroll
    for (int j = 0; j < 4; ++j) {
        int a0 = (EB ^ (j<<2)) + (j<<10);
        float2 wA = lds[a0], wB = lds[a0^1];
        float4 xv = xs[j];
        orow4[tid + (j<<9)] = make_float4(wA.y + xv.x*bc, wA.x + xv.y*bc,
                                          wB.y + xv.z*bc, wB.x + xv.w*bc);
    }
}

extern "C" void kernel_launch(void* const* d_in, const int* in_sizes, int n_in,
                              void* d_out, int out_size, void* d_ws, size_t ws_size,
                              hipStream_t stream) {
    const float* x      = (const float*)d_in[0];
    const float* z      = (const float*)d_in[2];
    const float* t      = (const float*)d_in[3];
    const float* deltas = (const float*)d_in[4];
    const float* freq   = (const float*)d_in[5];
    const float* W0     = (const float*)d_in[6];
    const float* b0     = (const float*)d_in[7];
    const float* W1     = (const float*)d_in[8];
    const float* b1     = (const float*)d_in[9];
    const float* W2     = (const float*)d_in[10];
    const float* b2     = (const float*)d_in[11];
    const float* W3     = (const float*)d_in[12];
    const float* b3     = (const float*)d_in[13];
    const float* bias   = (const float*)d_in[14];
    float* out = (float*)d_out;
    float* ws  = (float*)d_ws;
    float* H   = ws + OFF_H;
    float* Kf  = ws + OFF_KF;

    hipLaunchKernelGGL(k_pre, dim3(17), dim3(512), 0, stream, z, freq, W0, b0, W1, b1, W2, b2, ws, H);
    hipLaunchKernelGGL(k_filter, dim3(NCH), dim3(NT), 0, stream, H, t, deltas, W3, b3, ws, Kf);
    hipLaunchKernelGGL(k_main, dim3(NBATCH * NCH), dim3(NT), 0, stream, x, ws, Kf, bias, out);
}

// Round 2
// 784.116 us; speedup vs baseline: 1.0703x; 1.0703x over previous
//
#include <hip/hip_runtime.h>
#include <math.h>

// HyenaFilter: y = irfft(rfft(x,2L) * rfft(k,2L))[..., :L] + x*bias
// Register-blocked mixed-radix [16,16,16,2] FFT. This revision:
//  - hand-folded XOR-swizzle addressing (1 XOR/access, ds-offset-foldable)
//  - table twiddles (TL*TH factorization for pass A) replacing 14-deep cmul chains
//  - radix-2 passes fused into the spectral multiply (quad {k,4096-k,4096+k,8192-k})
//  - pruned first forward pass (upper half of input is zero)
//  - H in row-major [8192][16]; k_init+k_mlp merged into k_pre
//  - R1 fix: __launch_bounds__(NT) only — the (NT,4) min-waves clamp forced
//    VGPR=64 and spilled ~48 floats/thread (WRITE_SIZE 196->786 MB). LDS already
//    caps residency at 2 blocks/CU; let the allocator use ~96-128 VGPR.

#define LSEQ 8192
#define NCH 768
#define NBATCH 8
#define NT 512

// ws layout (float offsets) — all tables fit in the pre-H region (no growth vs prev)
#define OFF_TWB  0        // 32 rows x 16 float2 : W16384^{32*q*m}   (pass B)
#define OFF_TW16 1024     // 2049 float2         : W16384^k, k<=2048
#define OFF_TL   5124     // 32 rows x 16 float2 : W16384^{2*a*m}    (pass A low)
#define OFF_TH   6148     // 16 rows x 16 float2 : W16384^{64*b*m}   (pass A high)
#define OFF_TWC  6660     // 2 rows x 16 float2  : W16384^{512*p*m}  (pass C)
#define OFF_H    10240    // 8192 x 16 floats (MLP features, row-major)
#define OFF_KF   141312   // 768 x 4096 float4 (S~, D~ per bin pair)

__device__ __forceinline__ float2 cadd(float2 a, float2 b){ return make_float2(a.x+b.x, a.y+b.y); }
__device__ __forceinline__ float2 csub(float2 a, float2 b){ return make_float2(a.x-b.x, a.y-b.y); }
__device__ __forceinline__ float2 cmul(float2 a, float2 b){ return make_float2(a.x*b.x - a.y*b.y, a.x*b.y + a.y*b.x); }
__device__ __forceinline__ float2 mni(float2 a){ return make_float2(a.y, -a.x); }  // * -i

// generic swizzle (used only in the 4-iteration spectral stage)
__device__ __forceinline__ int IDX(int i){ return i ^ (((i>>4) ^ (i>>8)) & 15); }
// digit-reversal: bin k -> slot after DIF passes [16(512),16(32),16(2)] (pre-r2, slot even)
__device__ __forceinline__ int drev(int k){
    return ((k & 15) << 9) | (((k >> 4) & 15) << 5) | (((k >> 8) & 15) << 1) | (k >> 12);
}

#define C1 0.923879532511286756f
#define S1 0.382683432365089772f
#define R2 0.707106781186547524f

// natural-in DFT-16; output bin m in q[rv[m]]. FULL=false: inputs 8..15 are
// pre-duplicated copies of 0..7 (zero upper half), stage-1 add/sub skipped.
template<bool FULL>
__device__ __forceinline__ void dft16(float2 q[16]) {
    if constexpr (FULL) {
#pragma unroll
        for (int j = 0; j < 8; ++j) { float2 u=q[j], v=q[j+8]; q[j]=cadd(u,v); q[j+8]=csub(u,v); }
    }
    q[9]  = cmul(q[9],  make_float2( C1,-S1));
    q[10] = cmul(q[10], make_float2( R2,-R2));
    q[11] = cmul(q[11], make_float2( S1,-C1));
    q[12] = mni(q[12]);
    q[13] = cmul(q[13], make_float2(-S1,-C1));
    q[14] = cmul(q[14], make_float2(-R2,-R2));
    q[15] = cmul(q[15], make_float2(-C1,-S1));
#pragma unroll
    for (int b = 0; b < 16; b += 8) {
#pragma unroll
        for (int j = 0; j < 4; ++j) { float2 u=q[b+j], v=q[b+j+4]; q[b+j]=cadd(u,v); q[b+j+4]=csub(u,v); }
        q[b+5] = cmul(q[b+5], make_float2( R2,-R2));
        q[b+6] = mni(q[b+6]);
        q[b+7] = cmul(q[b+7], make_float2(-R2,-R2));
    }
#pragma unroll
    for (int b = 0; b < 16; b += 4) {
        float2 u0=q[b], v0=q[b+2], u1=q[b+1], v1=q[b+3];
        q[b]=cadd(u0,v0); q[b+2]=csub(u0,v0);
        q[b+1]=cadd(u1,v1); q[b+3]=mni(csub(u1,v1));
    }
#pragma unroll
    for (int b = 0; b < 16; b += 2) { float2 u=q[b], v=q[b+1]; q[b]=cadd(u,v); q[b+1]=csub(u,v); }
}

// Hand-folded swizzled addressing. For tid<512 the pass strides are bit-disjoint,
// so IDX(base+p+r*L) == (sb ^ C_r) + (r*L) with per-thread sb and constant C_r.
// (Verified numerically against IDX() for multiple (tid,r) samples per pass.)
template<int PASS>
__device__ __forceinline__ int psb(int tid) {
    if constexpr (PASS == 0) {               // L=512, p=tid
        return tid ^ (((tid>>4) ^ (tid>>8)) & 15);
    } else if constexpr (PASS == 1) {        // L=32, base=(tid>>5)<<9, p=tid&31
        int p = tid & 31, hb = tid >> 5;
        return ((hb<<9) | p) ^ (((p>>4) ^ (hb<<1)) & 15);
    } else {                                 // L=2, base=(tid>>1)<<5, p=tid&1
        int h = tid >> 1;
        return ((h<<5) | (tid&1)) ^ (((h<<1) ^ (h>>3)) & 15);
    }
}
template<int PASS>
__device__ __forceinline__ int paddr(int sb, int r) {
    if constexpr (PASS == 0)      return (sb ^ (2*(r&7))) + (r<<9);
    else if constexpr (PASS == 1) return (sb ^ ((2*(r&7)) ^ (r>>3))) + (r<<5);
    else                          return sb ^ ((r<<1) ^ (r>>3));
}

// twiddle row pointers (rows of 16 float2 = 8 float4, 128B aligned)
template<int PASS>
__device__ __forceinline__ void twrows(const float* ws, int tid, const float4*& rA, const float4*& rB) {
    if constexpr (PASS == 0) {
        rA = (const float4*)(ws + OFF_TL) + ((tid & 31) << 3);
        rB = (const float4*)(ws + OFF_TH) + ((tid >> 5) << 3);
    } else if constexpr (PASS == 1) {
        rA = (const float4*)(ws + OFF_TWB) + ((tid & 31) << 3); rB = rA;
    } else {
        rA = (const float4*)(ws + OFF_TWC) + ((tid & 1) << 3); rB = rA;
    }
}
template<int PASS>
__device__ __forceinline__ void twget(const float4* rA, const float4* rB, int j, float2& w0, float2& w1) {
    float4 a = rA[j];
    if constexpr (PASS == 0) {   // W^{p*m} = TL[p&31][m] * TH[p>>5][m]
        float4 b = rB[j];
        w0 = cmul(make_float2(a.x,a.y), make_float2(b.x,b.y));
        w1 = cmul(make_float2(a.z,a.w), make_float2(b.z,b.w));
    } else {
        w0 = make_float2(a.x, a.y);
        w1 = make_float2(a.z, a.w);
    }
}

// One radix-16 pass. DIT=false: dft16 then q[rv[m]] *= W^{pm} (DIF fwd).
// DIT=true: q[r] *= W^{pr} then dft16. PRUNED (fwd pass A only): upper 8 inputs zero.
template<int PASS, bool DIT, bool PRUNED>
__device__ __forceinline__ void r16p(float2* lds, int tid, const float* __restrict__ ws) {
    static constexpr int RV[16] = {0,8,4,12,2,10,6,14,1,9,5,13,3,11,7,15};
    const int sb = psb<PASS>(tid);
    const float4 *rA, *rB;
    twrows<PASS>(ws, tid, rA, rB);
    float2 q[16];
    if constexpr (PRUNED) {
#pragma unroll
        for (int r = 0; r < 8; ++r) { q[r] = lds[paddr<PASS>(sb, r)]; q[r+8] = q[r]; }
    } else {
#pragma unroll
        for (int r = 0; r < 16; ++r) q[r] = lds[paddr<PASS>(sb, r)];
    }
    if constexpr (DIT) {
#pragma unroll
        for (int j = 0; j < 8; ++j) {
            float2 w0, w1; twget<PASS>(rA, rB, j, w0, w1);
            if (j) q[2*j] = cmul(q[2*j], w0);
            q[2*j+1] = cmul(q[2*j+1], w1);
        }
        dft16<true>(q);
    } else {
        dft16<!PRUNED>(q);
#pragma unroll
        for (int j = 0; j < 8; ++j) {
            float2 w0, w1; twget<PASS>(rA, rB, j, w0, w1);
            if (j) q[RV[2*j]] = cmul(q[RV[2*j]], w0);
            q[RV[2*j+1]] = cmul(q[RV[2*j+1]], w1);
        }
    }
#pragma unroll
    for (int m = 0; m < 16; ++m) lds[paddr<PASS>(sb, m)] = q[RV[m]];
}

// spectral multiply for bin pair (k, 8192-k): o1/o2 are swapped v'[k], v'[8192-k]
__device__ __forceinline__ void specpair(float2 V1, float2 V2, float4 kv, float2 W,
                                         float2& o1, float2& o2) {
    float2 Eh = make_float2(V1.x + V2.x, V1.y - V2.y);
    float2 Oh = make_float2(V1.y + V2.y, V2.x - V1.x);
    float2 S = make_float2(kv.x, kv.y);
    float a = W.x*kv.z, b = W.y*kv.w, cc = W.x*kv.w, dd = W.y*kv.z;
    float2 T  = make_float2(a - b, cc + dd);
    float2 T2 = make_float2(a + b, cc - dd);
    float2 Ep = cadd(cmul(Eh, S), cmul(Oh, T));
    float2 Op = cadd(cmul(Eh, T2), cmul(Oh, S));
    o1 = make_float2(Ep.y + Op.x, Ep.x - Op.y);
    o2 = make_float2(Op.x - Ep.y, Ep.x + Op.y);
}

// merged init (block 0: twiddle tables via double-precision factor tables) + MLP (blocks 1..16)
__global__ __launch_bounds__(512) void k_pre(const float* __restrict__ z, const float* __restrict__ freq,
        const float* __restrict__ W0, const float* __restrict__ b0,
        const float* __restrict__ W1, const float* __restrict__ b1,
        const float* __restrict__ W2, const float* __restrict__ b2,
        float* __restrict__ ws, float* __restrict__ H) {
    __shared__ double2 lA[128], lB[128];
    const int t = threadIdx.x;
    if (blockIdx.x == 0) {
        const double K = -2.0 * 3.14159265358979323846 / 16384.0;
        if (t < 128)      { double a = K * (double)(t << 7); lA[t] = make_double2(cos(a), sin(a)); }
        else if (t < 256) { int b = t - 128; double a = K * (double)b; lB[b] = make_double2(cos(a), sin(a)); }
        __syncthreads();
        auto wf = [&](int e) -> float2 {
            e &= 16383;
            double2 A = lA[e >> 7], B = lB[e & 127];
            return make_float2((float)(A.x*B.x - A.y*B.y), (float)(A.x*B.y + A.y*B.x));
        };
        float2* tw16 = (float2*)(ws + OFF_TW16);
        for (int k = t; k <= 2048; k += 512) tw16[k] = wf(k);
        if (t < 32) {
            float2* rowL = (float2*)(ws + OFF_TL)  + (t << 4);
            float2* rowB = (float2*)(ws + OFF_TWB) + (t << 4);
#pragma unroll
            for (int m = 0; m < 16; ++m) { rowL[m] = wf(2*t*m); rowB[m] = wf(32*t*m); }
        } else if (t < 48) {
            int b = t - 32;
            float2* rowH = (float2*)(ws + OFF_TH) + (b << 4);
#pragma unroll
            for (int m = 0; m < 16; ++m) rowH[m] = wf(64*b*m);
        } else if (t < 50) {
            int c2 = t - 48;
            float2* rowC = (float2*)(ws + OFF_TWC) + (c2 << 4);
#pragma unroll
            for (int m = 0; m < 16; ++m) rowC[m] = wf(512*c2*m);
        }
    } else {
        const int j = ((blockIdx.x - 1) << 9) + t;
        const float z0 = z[j*3+0], z1 = z[j*3+1], z2 = z[j*3+2];
        float h[16], g[16];
#pragma unroll
        for (int m = 0; m < 16; ++m)
            h[m] = sinf(freq[m] * (z0*W0[m] + z1*W0[16+m] + z2*W0[32+m] + b0[m]));
#pragma unroll
        for (int m = 0; m < 16; ++m) {
            float a = b1[m];
#pragma unroll
            for (int p = 0; p < 16; ++p) a += h[p] * W1[p*16+m];
            g[m] = sinf(freq[m] * a);
        }
#pragma unroll
        for (int m = 0; m < 16; ++m) {
            float a = b2[m];
#pragma unroll
            for (int p = 0; p < 16; ++p) a += g[p] * W2[p*16+m];
            h[m] = sinf(freq[m] * a);
        }
        float4* hp = (float4*)(H + (j << 4));   // row-major [8192][16]
        hp[0] = make_float4(h[0],  h[1],  h[2],  h[3]);
        hp[1] = make_float4(h[4],  h[5],  h[6],  h[7]);
        hp[2] = make_float4(h[8],  h[9],  h[10], h[11]);
        hp[3] = make_float4(h[12], h[13], h[14], h[15]);
    }
}

// Per channel: filter -> pruned fwd FFT -> fused(r2+unpack) -> store (S~,D~)
__global__ __launch_bounds__(NT) void k_filter(const float* __restrict__ H, const float* __restrict__ t,
        const float* __restrict__ deltas, const float* __restrict__ W3,
        const float* __restrict__ b3, const float* __restrict__ ws,
        float* __restrict__ KfF) {
    __shared__ float2 lds[LSEQ];
    const int c = blockIdx.x;
    const int tid = threadIdx.x;
    float4 w3a = make_float4(W3[0*NCH+c],  W3[1*NCH+c],  W3[2*NCH+c],  W3[3*NCH+c]);
    float4 w3b = make_float4(W3[4*NCH+c],  W3[5*NCH+c],  W3[6*NCH+c],  W3[7*NCH+c]);
    float4 w3c = make_float4(W3[8*NCH+c],  W3[9*NCH+c],  W3[10*NCH+c], W3[11*NCH+c]);
    float4 w3d = make_float4(W3[12*NCH+c], W3[13*NCH+c], W3[14*NCH+c], W3[15*NCH+c]);
    const float b3c = b3[c];
    const float ad = fabsf(deltas[c]);
    const int sbA = psb<0>(tid);
#pragma unroll 2
    for (int j = 0; j < 8; ++j) {
        int n = tid + (j << 9);
        const float4* hp = (const float4*)(H + (n << 5));
        float4 p0 = hp[0], p1 = hp[1], p2 = hp[2], p3 = hp[3];
        float4 q0 = hp[4], q1 = hp[5], q2 = hp[6], q3 = hp[7];
        float s0 = b3c + p0.x*w3a.x + p0.y*w3a.y + p0.z*w3a.z + p0.w*w3a.w
                       + p1.x*w3b.x + p1.y*w3b.y + p1.z*w3b.z + p1.w*w3b.w
                       + p2.x*w3c.x + p2.y*w3c.y + p2.z*w3c.z + p2.w*w3c.w
                       + p3.x*w3d.x + p3.y*w3d.y + p3.z*w3d.z + p3.w*w3d.w;
        float s1 = b3c + q0.x*w3a.x + q0.y*w3a.y + q0.z*w3a.z + q0.w*w3a.w
                       + q1.x*w3b.x + q1.y*w3b.y + q1.z*w3b.z + q1.w*w3b.w
                       + q2.x*w3c.x + q2.y*w3c.y + q2.z*w3c.z + q2.w*w3c.w
                       + q3.x*w3d.x + q3.y*w3d.y + q3.z*w3d.z + q3.w*w3d.w;
        float2 tv = ((const float2*)t)[n];
        lds[(sbA ^ (2*j)) + (j<<9)] = make_float2(s0 * expf(-tv.x*ad), s1 * expf(-tv.y*ad));
    }
    __syncthreads();
    r16p<0,false,true >(lds, tid, ws); __syncthreads();
    r16p<1,false,false>(lds, tid, ws); __syncthreads();
    r16p<2,false,false>(lds, tid, ws); __syncthreads();

    float4* kf4 = (float4*)KfF + (size_t)c * 4096;
    const float2* tw16 = (const float2*)(ws + OFF_TW16);
    const float sc = 1.0f / 32768.0f;
#pragma unroll 2
    for (int it = 0; it < 4; ++it) {
        int k  = tid + 1 + (it << 9);   // 1..2048
        int jj = 4096 - k;              // 2048..4095 (k=2048: idempotent dup)
        int pA = IDX(drev(k)), pB = IDX(drev(jj));
        float2 uA = lds[pA], vA = lds[pA^1];
        float2 uB = lds[pB], vB = lds[pB^1];
        float2 Vk = cadd(uA, vA), Vk4 = csub(uA, vA);   // bins k, k+4096
        float2 Vj = cadd(uB, vB), Vj4 = csub(uB, vB);   // bins jj, jj+4096 (=8192-k)
        float2 W  = tw16[k];
        float2 Wj = make_float2(-W.y, -W.x);            // tw16[4096-k]
        {
            float2 E = make_float2(Vk.x + Vj4.x, Vk.y - Vj4.y);
            float2 O = make_float2(Vk.y + Vj4.y, Vj4.x - Vk.x);
            float2 D = cmul(W, O);
            kf4[k] = make_float4(E.x*sc, E.y*sc, D.x*sc, D.y*sc);
        }
        {
            float2 E = make_float2(Vj.x + Vk4.x, Vj.y - Vk4.y);
            float2 O = make_float2(Vj.y + Vk4.y, Vk4.x - Vj.x);
            float2 D = cmul(Wj, O);
            kf4[jj] = make_float4(E.x*sc, E.y*sc, D.x*sc, D.y*sc);
        }
    }
    if (tid == 0) {
        float2 u = lds[0], v = lds[1];          // IDX(0)=0, IDX(1)=1
        float2 V0 = cadd(u, v), VN = csub(u, v);
        kf4[0] = make_float4((V0.x + V0.y)/16384.f, (V0.x - V0.y)/16384.f,
                             VN.x/8192.f, -VN.y/8192.f);
    }
}

// Per row: pack x -> pruned fwd FFT -> fused(r2 + spectral + inv-r2) -> DIT net -> out
__global__ __launch_bounds__(NT) void k_main(const float* __restrict__ x, const float* __restrict__ ws,
        const float* __restrict__ KfF, const float* __restrict__ bias,
        float* __restrict__ out) {
    __shared__ float2 lds[LSEQ];
    const int bid = blockIdx.x;
    const int c = bid >> 3, bat = bid & 7;     // co-resident batches share Kf[c] in L2
    const int row = bat * NCH + c;
    const int tid = threadIdx.x;
    const float4* xrow4 = (const float4*)(x + (size_t)row * LSEQ);
    const float4* kf4 = (const float4*)KfF + (size_t)c * 4096;

    // staging addresses: IDX(2i) = (EB ^ (j<<2)) + (j<<10), IDX(2i+1) = that ^ 1
    const int EB = (tid << 1) ^ (((tid>>3) ^ (tid>>7)) & 15);
    float4 xs[4];
#pragma unroll
    for (int j = 0; j < 4; ++j) {
        float4 v = xrow4[tid + (j<<9)];
        xs[j] = v;
        int a0 = (EB ^ (j<<2)) + (j<<10);
        lds[a0]   = make_float2(v.x, v.y);
        lds[a0^1] = make_float2(v.z, v.w);
    }
    __syncthreads();
    r16p<0,false,true >(lds, tid, ws); __syncthreads();
    r16p<1,false,false>(lds, tid, ws); __syncthreads();
    r16p<2,false,false>(lds, tid, ws); __syncthreads();

    // fused fwd-r2 + spectral multiply + inverse-r2, per closed quad of bins
    {
        const float2* tw16 = (const float2*)(ws + OFF_TW16);
#pragma unroll 2
        for (int it = 0; it < 4; ++it) {
            int k  = tid + 1 + (it << 9);   // 1..2048
            int jj = 4096 - k;
            int pA = IDX(drev(k)), pB = IDX(drev(jj));
            float2 uA = lds[pA], vA = lds[pA^1];
            float2 uB = lds[pB], vB = lds[pB^1];
            float2 Vk = cadd(uA, vA), Vk4 = csub(uA, vA);   // bins k, k+4096
            float2 Vj = cadd(uB, vB), Vj4 = csub(uB, vB);   // bins jj, 8192-k
            float4 kvk = kf4[k], kvj = kf4[jj];
            float2 W  = tw16[k];
            float2 Wj = make_float2(-W.y, -W.x);
            float2 r1, r2, r1j, r2j;
            specpair(Vk, Vj4, kvk, W,  r1,  r2);   // v'[k],  v'[8192-k]
            specpair(Vj, Vk4, kvj, Wj, r1j, r2j);  // v'[jj], v'[4096+k]
            lds[pA]   = cadd(r1, r2j);  lds[pA^1] = csub(r1, r2j);
            lds[pB]   = cadd(r1j, r2);  lds[pB^1] = csub(r1j, r2);
        }
        if (tid == 0) {
            float2 u = lds[0], v = lds[1];
            float2 V0 = cadd(u, v), VN = csub(u, v);        // bins 0, 4096
            float4 kv = kf4[0];
            float U0 = V0.x + V0.y, UL = V0.x - V0.y;
            float re = U0*kv.x + UL*kv.y;
            float im = U0*kv.x - UL*kv.y;
            float2 s0 = make_float2(im, re);
            float2 P = make_float2(VN.x*kv.z + VN.y*kv.w, VN.x*kv.w - VN.y*kv.z);
            float2 s1 = make_float2(-P.y, P.x);
            lds[0] = cadd(s0, s1);
            lds[1] = csub(s0, s1);
        }
    }
    __syncthreads();

    r16p<2,true,false>(lds, tid, ws); __syncthreads();
    r16p<1,true,false>(lds, tid, ws); __syncthreads();
    r16p<0,true,false>(lds, tid, ws); __syncthreads();

    const float bc = bias[c];
    float4* orow4 = (float4*)(out + (size_t)row * LSEQ);
#pragma unroll
    for (int j = 0; j < 4; ++j) {
        int a0 = (EB ^ (j<<2)) + (j<<10);
        float2 wA = lds[a0], wB = lds[a0^1];
        float4 xv = xs[j];
        orow4[tid + (j<<9)] = make_float4(wA.y + xv.x*bc, wA.x + xv.y*bc,
                                          wB.y + xv.z*bc, wB.x + xv.w*bc);
    }
}

extern "C" void kernel_launch(void* const* d_in, const int* in_sizes, int n_in,
                              void* d_out, int out_size, void* d_ws, size_t ws_size,
                              hipStream_t stream) {
    const float* x      = (const float*)d_in[0];
    const float* z      = (const float*)d_in[2];
    const float* t      = (const float*)d_in[3];
    const float* deltas = (const float*)d_in[4];
    const float* freq   = (const float*)d_in[5];
    const float* W0     = (const float*)d_in[6];
    const float* b0     = (const float*)d_in[7];
    const float* W1     = (const float*)d_in[8];
    const float* b1     = (const float*)d_in[9];
    const float* W2     = (const float*)d_in[10];
    const float* b2     = (const float*)d_in[11];
    const float* W3     = (const float*)d_in[12];
    const float* b3     = (const float*)d_in[13];
    const float* bias   = (const float*)d_in[14];
    float* out = (float*)d_out;
    float* ws  = (float*)d_ws;
    float* H   = ws + OFF_H;
    float* Kf  = ws + OFF_KF;

    hipLaunchKernelGGL(k_pre, dim3(17), dim3(512), 0, stream, z, freq, W0, b0, W1, b1, W2, b2, ws, H);
    hipLaunchKernelGGL(k_filter, dim3(NCH), dim3(NT), 0, stream, H, t, deltas, W3, b3, ws, Kf);
    hipLaunchKernelGGL(k_main, dim3(NBATCH * NCH), dim3(NT), 0, stream, x, ws, Kf, bias, out);
}

// Round 3
// 661.860 us; speedup vs baseline: 1.2681x; 1.1847x over previous
//
#include <hip/hip_runtime.h>
#include <math.h>

// HyenaFilter: y = irfft(rfft(x,2L) * rfft(k,2L))[..., :L] + x*bias
// Register-blocked mixed-radix [16,16,16,2] FFT. Round-3 revision:
//  - twiddle row tables live in LDS (transposed [m][row], 2-way-bank = free),
//    fixing round-2's post-barrier L1 burst stall. Pass-A high factor = TWB[2b].
//  - B<->C exchanges are wave-local (32-consecutive-thread groups) -> replace
//    2 full barriers with s_waitcnt lgkmcnt(0).
//  - k_main: 4 rows per block (grid 1536 = 3 exact residency rounds); table copy
//    amortized, kf4/tw16 L1-hot across rows, next row's x prefetched into regs.
//  - keeps: folded XOR-swizzle addressing, fused r2+spectral quad stage, pruned
//    first fwd pass, row-major H, merged k_pre. No min-waves clamp (R1 lesson);
//    VGPR must stay <=128 for 16 waves/CU.

#define LSEQ 8192
#define NCH 768
#define NBATCH 8
#define NT 512

// ws layout (float offsets)
#define OFF_TWB  0        // 32 rows x 16 float2 : W16384^{32*q*m}   (pass B; pass-A high = rows 2b)
#define OFF_TW16 1024     // 2049 float2         : W16384^k, k<=2048
#define OFF_TL   5124     // 32 rows x 16 float2 : W16384^{2*a*m}    (pass A low)
#define OFF_TWC  6660     // 2 rows x 16 float2  : W16384^{512*p*m}  (pass C)
#define OFF_H    10240    // 8192 x 16 floats (MLP features, row-major)
#define OFF_KF   141312   // 768 x 4096 float4 (S~, D~ per bin pair)

__device__ __forceinline__ float2 cadd(float2 a, float2 b){ return make_float2(a.x+b.x, a.y+b.y); }
__device__ __forceinline__ float2 csub(float2 a, float2 b){ return make_float2(a.x-b.x, a.y-b.y); }
__device__ __forceinline__ float2 cmul(float2 a, float2 b){ return make_float2(a.x*b.x - a.y*b.y, a.x*b.y + a.y*b.x); }
__device__ __forceinline__ float2 mni(float2 a){ return make_float2(a.y, -a.x); }  // * -i

// wave-local LDS producer->consumer sync (exchange confined to one wave):
// LDS ops of a wave complete in order; lgkmcnt(0) + compiler memory barrier.
__device__ __forceinline__ void wave_sync(){
    asm volatile("s_waitcnt lgkmcnt(0)" ::: "memory");
}

// generic swizzle (used only in the spectral stage)
__device__ __forceinline__ int IDX(int i){ return i ^ (((i>>4) ^ (i>>8)) & 15); }
// digit-reversal: bin k -> slot after DIF passes [16(512),16(32),16(2)] (pre-r2, slot even)
__device__ __forceinline__ int drev(int k){
    return ((k & 15) << 9) | (((k >> 4) & 15) << 5) | (((k >> 8) & 15) << 1) | (k >> 12);
}

#define C1 0.923879532511286756f
#define S1 0.382683432365089772f
#define R2 0.707106781186547524f

// natural-in DFT-16; output bin m in q[rv[m]]. FULL=false: inputs 8..15 are
// pre-duplicated copies of 0..7 (zero upper half), stage-1 add/sub skipped.
template<bool FULL>
__device__ __forceinline__ void dft16(float2 q[16]) {
    if constexpr (FULL) {
#pragma unroll
        for (int j = 0; j < 8; ++j) { float2 u=q[j], v=q[j+8]; q[j]=cadd(u,v); q[j+8]=csub(u,v); }
    }
    q[9]  = cmul(q[9],  make_float2( C1,-S1));
    q[10] = cmul(q[10], make_float2( R2,-R2));
    q[11] = cmul(q[11], make_float2( S1,-C1));
    q[12] = mni(q[12]);
    q[13] = cmul(q[13], make_float2(-S1,-C1));
    q[14] = cmul(q[14], make_float2(-R2,-R2));
    q[15] = cmul(q[15], make_float2(-C1,-S1));
#pragma unroll
    for (int b = 0; b < 16; b += 8) {
#pragma unroll
        for (int j = 0; j < 4; ++j) { float2 u=q[b+j], v=q[b+j+4]; q[b+j]=cadd(u,v); q[b+j+4]=csub(u,v); }
        q[b+5] = cmul(q[b+5], make_float2( R2,-R2));
        q[b+6] = mni(q[b+6]);
        q[b+7] = cmul(q[b+7], make_float2(-R2,-R2));
    }
#pragma unroll
    for (int b = 0; b < 16; b += 4) {
        float2 u0=q[b], v0=q[b+2], u1=q[b+1], v1=q[b+3];
        q[b]=cadd(u0,v0); q[b+2]=csub(u0,v0);
        q[b+1]=cadd(u1,v1); q[b+3]=mni(csub(u1,v1));
    }
#pragma unroll
    for (int b = 0; b < 16; b += 2) { float2 u=q[b], v=q[b+1]; q[b]=cadd(u,v); q[b+1]=csub(u,v); }
}

// Hand-folded swizzled addressing: IDX(base+p+r*L) == (sb ^ C_r) + (r*L).
template<int PASS>
__device__ __forceinline__ int psb(int tid) {
    if constexpr (PASS == 0) {               // L=512, p=tid
        return tid ^ (((tid>>4) ^ (tid>>8)) & 15);
    } else if constexpr (PASS == 1) {        // L=32, base=(tid>>5)<<9, p=tid&31
        int p = tid & 31, hb = tid >> 5;
        return ((hb<<9) | p) ^ (((p>>4) ^ (hb<<1)) & 15);
    } else {                                 // L=2, base=(tid>>1)<<5, p=tid&1
        int h = tid >> 1;
        return ((h<<5) | (tid&1)) ^ (((h<<1) ^ (h>>3)) & 15);
    }
}
template<int PASS>
__device__ __forceinline__ int paddr(int sb, int r) {
    if constexpr (PASS == 0)      return (sb ^ (2*(r&7))) + (r<<9);
    else if constexpr (PASS == 1) return (sb ^ ((2*(r&7)) ^ (r>>3))) + (r<<5);
    else                          return sb ^ ((r<<1) ^ (r>>3));
}

// One radix-16 pass, twiddles from LDS table twT[m][row]:
//   row<32: TWB[q][m]=W16384^{32qm}; row=32+a: TL[a][m]=W16384^{2am}; row=64+c: TWC[c][m].
// Pass A twiddle W8192^{pm} = TL[p&31][m] * TWB[2*(p>>5)][m].
// DIT=false: dft16 then q[rv[m]] *= W^{pm}. DIT=true: q[r] *= W^{pr} then dft16.
template<int PASS, bool DIT, bool PRUNED>
__device__ __forceinline__ void r16p(float2* lds, const float2 (*twT)[68], int tid) {
    static constexpr int RV[16] = {0,8,4,12,2,10,6,14,1,9,5,13,3,11,7,15};
    const int sb = psb<PASS>(tid);
    int rL, rH = 0;
    if constexpr (PASS == 0) { rL = 32 + (tid & 31); rH = (tid >> 5) << 1; }
    else if constexpr (PASS == 1) { rL = tid & 31; }
    else { rL = 64 + (tid & 1); }
    float2 q[16];
    if constexpr (PRUNED) {
#pragma unroll
        for (int r = 0; r < 8; ++r) { q[r] = lds[paddr<PASS>(sb, r)]; q[r+8] = q[r]; }
    } else {
#pragma unroll
        for (int r = 0; r < 16; ++r) q[r] = lds[paddr<PASS>(sb, r)];
    }
    if constexpr (DIT) {
#pragma unroll
        for (int m = 1; m < 16; ++m) {
            float2 w = twT[m][rL];
            if constexpr (PASS == 0) w = cmul(w, twT[m][rH]);
            q[m] = cmul(q[m], w);
        }
        dft16<true>(q);
    } else {
        dft16<!PRUNED>(q);
#pragma unroll
        for (int m = 1; m < 16; ++m) {
            float2 w = twT[m][rL];
            if constexpr (PASS == 0) w = cmul(w, twT[m][rH]);
            q[RV[m]] = cmul(q[RV[m]], w);
        }
    }
#pragma unroll
    for (int m = 0; m < 16; ++m) lds[paddr<PASS>(sb, m)] = q[RV[m]];
}

// copy twiddle tables global -> LDS (transposed): 66 rows x 16 elems
__device__ __forceinline__ void load_twT(float2 (*twT)[68], const float* __restrict__ ws, int tid) {
    const float2* gTWB = (const float2*)(ws + OFF_TWB);
    const float2* gTL  = (const float2*)(ws + OFF_TL);
    const float2* gTWC = (const float2*)(ws + OFF_TWC);
    for (int idx = tid; idx < 16*66; idx += NT) {
        int r = idx >> 4, m = idx & 15;
        float2 v;
        if (r < 32)      v = gTWB[(r << 4) + m];
        else if (r < 64) v = gTL[((r - 32) << 4) + m];
        else             v = gTWC[((r - 64) << 4) + m];
        twT[m][r] = v;
    }
}

// spectral multiply for bin pair (k, 8192-k): o1/o2 are swapped v'[k], v'[8192-k]
__device__ __forceinline__ void specpair(float2 V1, float2 V2, float4 kv, float2 W,
                                         float2& o1, float2& o2) {
    float2 Eh = make_float2(V1.x + V2.x, V1.y - V2.y);
    float2 Oh = make_float2(V1.y + V2.y, V2.x - V1.x);
    float2 S = make_float2(kv.x, kv.y);
    float a = W.x*kv.z, b = W.y*kv.w, cc = W.x*kv.w, dd = W.y*kv.z;
    float2 T  = make_float2(a - b, cc + dd);
    float2 T2 = make_float2(a + b, cc - dd);
    float2 Ep = cadd(cmul(Eh, S), cmul(Oh, T));
    float2 Op = cadd(cmul(Eh, T2), cmul(Oh, S));
    o1 = make_float2(Ep.y + Op.x, Ep.x - Op.y);
    o2 = make_float2(Op.x - Ep.y, Ep.x + Op.y);
}

// merged init (block 0: twiddle tables via double-precision factor tables) + MLP (blocks 1..16)
__global__ __launch_bounds__(512) void k_pre(const float* __restrict__ z, const float* __restrict__ freq,
        const float* __restrict__ W0, const float* __restrict__ b0,
        const float* __restrict__ W1, const float* __restrict__ b1,
        const float* __restrict__ W2, const float* __restrict__ b2,
        float* __restrict__ ws, float* __restrict__ H) {
    __shared__ double2 lA[128], lB[128];
    const int t = threadIdx.x;
    if (blockIdx.x == 0) {
        const double K = -2.0 * 3.14159265358979323846 / 16384.0;
        if (t < 128)      { double a = K * (double)(t << 7); lA[t] = make_double2(cos(a), sin(a)); }
        else if (t < 256) { int b = t - 128; double a = K * (double)b; lB[b] = make_double2(cos(a), sin(a)); }
        __syncthreads();
        auto wf = [&](int e) -> float2 {
            e &= 16383;
            double2 A = lA[e >> 7], B = lB[e & 127];
            return make_float2((float)(A.x*B.x - A.y*B.y), (float)(A.x*B.y + A.y*B.x));
        };
        float2* tw16 = (float2*)(ws + OFF_TW16);
        for (int k = t; k <= 2048; k += 512) tw16[k] = wf(k);
        if (t < 32) {
            float2* rowL = (float2*)(ws + OFF_TL)  + (t << 4);
            float2* rowB = (float2*)(ws + OFF_TWB) + (t << 4);
#pragma unroll
            for (int m = 0; m < 16; ++m) { rowL[m] = wf(2*t*m); rowB[m] = wf(32*t*m); }
        } else if (t < 34) {
            int c2 = t - 32;
            float2* rowC = (float2*)(ws + OFF_TWC) + (c2 << 4);
#pragma unroll
            for (int m = 0; m < 16; ++m) rowC[m] = wf(512*c2*m);
        }
    } else {
        const int j = ((blockIdx.x - 1) << 9) + t;
        const float z0 = z[j*3+0], z1 = z[j*3+1], z2 = z[j*3+2];
        float h[16], g[16];
#pragma unroll
        for (int m = 0; m < 16; ++m)
            h[m] = sinf(freq[m] * (z0*W0[m] + z1*W0[16+m] + z2*W0[32+m] + b0[m]));
#pragma unroll
        for (int m = 0; m < 16; ++m) {
            float a = b1[m];
#pragma unroll
            for (int p = 0; p < 16; ++p) a += h[p] * W1[p*16+m];
            g[m] = sinf(freq[m] * a);
        }
#pragma unroll
        for (int m = 0; m < 16; ++m) {
            float a = b2[m];
#pragma unroll
            for (int p = 0; p < 16; ++p) a += g[p] * W2[p*16+m];
            h[m] = sinf(freq[m] * a);
        }
        float4* hp = (float4*)(H + (j << 4));   // row-major [8192][16]
        hp[0] = make_float4(h[0],  h[1],  h[2],  h[3]);
        hp[1] = make_float4(h[4],  h[5],  h[6],  h[7]);
        hp[2] = make_float4(h[8],  h[9],  h[10], h[11]);
        hp[3] = make_float4(h[12], h[13], h[14], h[15]);
    }
}

// Per channel: filter -> pruned fwd FFT -> fused(r2+unpack) -> store (S~,D~)
__global__ __launch_bounds__(NT) void k_filter(const float* __restrict__ H, const float* __restrict__ t,
        const float* __restrict__ deltas, const float* __restrict__ W3,
        const float* __restrict__ b3, const float* __restrict__ ws,
        float* __restrict__ KfF) {
    __shared__ float2 lds[LSEQ];
    __shared__ float2 twT[16][68];
    const int c = blockIdx.x;
    const int tid = threadIdx.x;
    load_twT(twT, ws, tid);
    float4 w3a = make_float4(W3[0*NCH+c],  W3[1*NCH+c],  W3[2*NCH+c],  W3[3*NCH+c]);
    float4 w3b = make_float4(W3[4*NCH+c],  W3[5*NCH+c],  W3[6*NCH+c],  W3[7*NCH+c]);
    float4 w3c = make_float4(W3[8*NCH+c],  W3[9*NCH+c],  W3[10*NCH+c], W3[11*NCH+c]);
    float4 w3d = make_float4(W3[12*NCH+c], W3[13*NCH+c], W3[14*NCH+c], W3[15*NCH+c]);
    const float b3c = b3[c];
    const float ad = fabsf(deltas[c]);
    const int sbA = psb<0>(tid);
#pragma unroll 2
    for (int j = 0; j < 8; ++j) {
        int n = tid + (j << 9);
        const float4* hp = (const float4*)(H + (n << 5));
        float4 p0 = hp[0], p1 = hp[1], p2 = hp[2], p3 = hp[3];
        float4 q0 = hp[4], q1 = hp[5], q2 = hp[6], q3 = hp[7];
        float s0 = b3c + p0.x*w3a.x + p0.y*w3a.y + p0.z*w3a.z + p0.w*w3a.w
                       + p1.x*w3b.x + p1.y*w3b.y + p1.z*w3b.z + p1.w*w3b.w
                       + p2.x*w3c.x + p2.y*w3c.y + p2.z*w3c.z + p2.w*w3c.w
                       + p3.x*w3d.x + p3.y*w3d.y + p3.z*w3d.z + p3.w*w3d.w;
        float s1 = b3c + q0.x*w3a.x + q0.y*w3a.y + q0.z*w3a.z + q0.w*w3a.w
                       + q1.x*w3b.x + q1.y*w3b.y + q1.z*w3b.z + q1.w*w3b.w
                       + q2.x*w3c.x + q2.y*w3c.y + q2.z*w3c.z + q2.w*w3c.w
                       + q3.x*w3d.x + q3.y*w3d.y + q3.z*w3d.z + q3.w*w3d.w;
        float2 tv = ((const float2*)t)[n];
        lds[(sbA ^ (2*j)) + (j<<9)] = make_float2(s0 * expf(-tv.x*ad), s1 * expf(-tv.y*ad));
    }
    __syncthreads();
    r16p<0,false,true >(lds, twT, tid); __syncthreads();
    r16p<1,false,false>(lds, twT, tid); wave_sync();
    r16p<2,false,false>(lds, twT, tid); __syncthreads();

    float4* kf4 = (float4*)KfF + (size_t)c * 4096;
    const float2* tw16 = (const float2*)(ws + OFF_TW16);
    const float sc = 1.0f / 32768.0f;
#pragma unroll 2
    for (int it = 0; it < 4; ++it) {
        int k  = tid + 1 + (it << 9);   // 1..2048
        int jj = 4096 - k;              // 2048..4095 (k=2048: idempotent dup)
        int pA = IDX(drev(k)), pB = IDX(drev(jj));
        float2 uA = lds[pA], vA = lds[pA^1];
        float2 uB = lds[pB], vB = lds[pB^1];
        float2 Vk = cadd(uA, vA), Vk4 = csub(uA, vA);   // bins k, k+4096
        float2 Vj = cadd(uB, vB), Vj4 = csub(uB, vB);   // bins jj, jj+4096 (=8192-k)
        float2 W  = tw16[k];
        float2 Wj = make_float2(-W.y, -W.x);            // tw16[4096-k]
        {
            float2 E = make_float2(Vk.x + Vj4.x, Vk.y - Vj4.y);
            float2 O = make_float2(Vk.y + Vj4.y, Vj4.x - Vk.x);
            float2 D = cmul(W, O);
            kf4[k] = make_float4(E.x*sc, E.y*sc, D.x*sc, D.y*sc);
        }
        {
            float2 E = make_float2(Vj.x + Vk4.x, Vj.y - Vk4.y);
            float2 O = make_float2(Vj.y + Vk4.y, Vk4.x - Vj.x);
            float2 D = cmul(Wj, O);
            kf4[jj] = make_float4(E.x*sc, E.y*sc, D.x*sc, D.y*sc);
        }
    }
    if (tid == 0) {
        float2 u = lds[0], v = lds[1];          // IDX(0)=0, IDX(1)=1
        float2 V0 = cadd(u, v), VN = csub(u, v);
        kf4[0] = make_float4((V0.x + V0.y)/16384.f, (V0.x - V0.y)/16384.f,
                             VN.x/8192.f, -VN.y/8192.f);
    }
}

// Per 4 rows (same channel): pack x -> pruned fwd FFT -> fused(r2+spectral+inv-r2)
// -> DIT net -> out. Next row's x prefetched into regs during current row's FFT.
__global__ __launch_bounds__(NT) void k_main(const float* __restrict__ x, const float* __restrict__ ws,
        const float* __restrict__ KfF, const float* __restrict__ bias,
        float* __restrict__ out) {
    __shared__ float2 lds[LSEQ];
    __shared__ float2 twT[16][68];
    const int bid = blockIdx.x;                 // 0..1535
    const int c = bid >> 1, half = bid & 1;     // 4 batches per block, same channel
    const int tid = threadIdx.x;
    const float4* kf4 = (const float4*)KfF + (size_t)c * 4096;
    const float2* tw16 = (const float2*)(ws + OFF_TW16);
    const size_t rowstride = (size_t)NCH * LSEQ;
    const float* xbase = x + (size_t)(half*4) * rowstride + (size_t)c * LSEQ;
    float* obase = out + (size_t)(half*4) * rowstride + (size_t)c * LSEQ;
    const float bc = bias[c];

    // staging addresses: IDX(2i) = (EB ^ (j<<2)) + (j<<10), IDX(2i+1) = that ^ 1
    const int EB = (tid << 1) ^ (((tid>>3) ^ (tid>>7)) & 15);

    float4 pf[4];
#pragma unroll
    for (int j = 0; j < 4; ++j) pf[j] = ((const float4*)xbase)[tid + (j<<9)];
    load_twT(twT, ws, tid);

    for (int rr = 0; rr < 4; ++rr) {
        float4 xs[4];
#pragma unroll
        for (int j = 0; j < 4; ++j) {
            xs[j] = pf[j];
            int a0 = (EB ^ (j<<2)) + (j<<10);
            lds[a0]   = make_float2(xs[j].x, xs[j].y);
            lds[a0^1] = make_float2(xs[j].z, xs[j].w);
        }
        if (rr < 3) {   // prefetch next row's x; hidden under this row's FFT
            const float4* xn = (const float4*)(xbase + (size_t)(rr+1) * rowstride);
#pragma unroll
            for (int j = 0; j < 4; ++j) pf[j] = xn[tid + (j<<9)];
        }
        __syncthreads();                              // also covers twT copy (rr==0)
        r16p<0,false,true >(lds, twT, tid); __syncthreads();
        r16p<1,false,false>(lds, twT, tid); wave_sync();
        r16p<2,false,false>(lds, twT, tid); __syncthreads();

        // fused fwd-r2 + spectral multiply + inverse-r2, per closed quad of bins
#pragma unroll 2
        for (int it = 0; it < 4; ++it) {
            int k  = tid + 1 + (it << 9);   // 1..2048
            int jj = 4096 - k;
            int pA = IDX(drev(k)), pB = IDX(drev(jj));
            float2 uA = lds[pA], vA = lds[pA^1];
            float2 uB = lds[pB], vB = lds[pB^1];
            float2 Vk = cadd(uA, vA), Vk4 = csub(uA, vA);   // bins k, k+4096
            float2 Vj = cadd(uB, vB), Vj4 = csub(uB, vB);   // bins jj, 8192-k
            float4 kvk = kf4[k], kvj = kf4[jj];
            float2 W  = tw16[k];
            float2 Wj = make_float2(-W.y, -W.x);
            float2 r1, r2, r1j, r2j;
            specpair(Vk, Vj4, kvk, W,  r1,  r2);   // v'[k],  v'[8192-k]
            specpair(Vj, Vk4, kvj, Wj, r1j, r2j);  // v'[jj], v'[4096+k]
            lds[pA]   = cadd(r1, r2j);  lds[pA^1] = csub(r1, r2j);
            lds[pB]   = cadd(r1j, r2);  lds[pB^1] = csub(r1j, r2);
        }
        if (tid == 0) {
            float2 u = lds[0], v = lds[1];
            float2 V0 = cadd(u, v), VN = csub(u, v);        // bins 0, 4096
            float4 kv = kf4[0];
            float U0 = V0.x + V0.y, UL = V0.x - V0.y;
            float re = U0*kv.x + UL*kv.y;
            float im = U0*kv.x - UL*kv.y;
            float2 s0 = make_float2(im, re);
            float2 P = make_float2(VN.x*kv.z + VN.y*kv.w, VN.x*kv.w - VN.y*kv.z);
            float2 s1 = make_float2(-P.y, P.x);
            lds[0] = cadd(s0, s1);
            lds[1] = csub(s0, s1);
        }
        __syncthreads();

        r16p<2,true,false>(lds, twT, tid); wave_sync();
        r16p<1,true,false>(lds, twT, tid); __syncthreads();
        r16p<0,true,false>(lds, twT, tid); __syncthreads();

        float4* orow4 = (float4*)(obase + (size_t)rr * rowstride);
#pragma unroll
        for (int j = 0; j < 4; ++j) {
            int a0 = (EB ^ (j<<2)) + (j<<10);
            float2 wA = lds[a0], wB = lds[a0^1];
            float4 xv = xs[j];
            orow4[tid + (j<<9)] = make_float4(wA.y + xv.x*bc, wA.x + xv.y*bc,
                                              wB.y + xv.z*bc, wB.x + xv.w*bc);
        }
        if (rr < 3) __syncthreads();   // protect lds before next row's staging
    }
}

extern "C" void kernel_launch(void* const* d_in, const int* in_sizes, int n_in,
                              void* d_out, int out_size, void* d_ws, size_t ws_size,
                              hipStream_t stream) {
    const float* x      = (const float*)d_in[0];
    const float* z      = (const float*)d_in[2];
    const float* t      = (const float*)d_in[3];
    const float* deltas = (const float*)d_in[4];
    const float* freq   = (const float*)d_in[5];
    const float* W0     = (const float*)d_in[6];
    const float* b0     = (const float*)d_in[7];
    const float* W1     = (const float*)d_in[8];
    const float* b1     = (const float*)d_in[9];
    const float* W2     = (const float*)d_in[10];
    const float* b2     = (const float*)d_in[11];
    const float* W3     = (const float*)d_in[12];
    const float* b3     = (const float*)d_in[13];
    const float* bias   = (const float*)d_in[14];
    float* out = (float*)d_out;
    float* ws  = (float*)d_ws;
    float* H   = ws + OFF_H;
    float* Kf  = ws + OFF_KF;

    hipLaunchKernelGGL(k_pre, dim3(17), dim3(512), 0, stream, z, freq, W0, b0, W1, b1, W2, b2, ws, H);
    hipLaunchKernelGGL(k_filter, dim3(NCH), dim3(NT), 0, stream, H, t, deltas, W3, b3, ws, Kf);
    hipLaunchKernelGGL(k_main, dim3(NBATCH * NCH / 4), dim3(NT), 0, stream, x, ws, Kf, bias, out);
}